// Round 1
// baseline (1163.686 us; speedup 1.0000x reference)
//
#include <hip/hip_runtime.h>

// ---------------------------------------------------------------------------
// AttentionLayer fused implementation for MI355X (gfx950)
// D=H=1024, B=128, R=512, M=B*R=65536
//
// Pipeline:
//  K1  wvt_kernel     : WvT bf16[n][k] = (bf16)Wv[k][n]            (2 MB ws)
//  K2  dual_gemm_k    : s_proj=relu(s_t@Wsp+bsp), h_proj=tanh(h_t@Whp+bhp)
//  K3  dual_gemm_k    : s_att=s_proj@Wsa+bsa,     h_att=h_proj@Wha+bha
//      memsetAsync    : scores[B][513] = 0
//  K5  score_gemm_k   : fused bf16 MFMA GEMM (V@Wv) + relu/tanh/Wal-dot
//                       epilogue -> atomicAdd scores[b][r]   (bal dropped:
//                       softmax-invariant constant)
//  K6  lastrow_k      : scores[b][512] = sum_h Wal*tanh(s_att+h_att)
//  K7  softmax_k      : alpha = softmax(scores, axis=1)
//  K8  ctx_k          : ctxsum = alpha@[V;s_proj] + h_proj
//  K9  dual_gemm_k    : out = tanh(ctxsum@Wcp + bcp)
// ---------------------------------------------------------------------------

typedef __bf16 bf16x8 __attribute__((ext_vector_type(8)));
typedef float floatx4 __attribute__((ext_vector_type(4)));

__device__ __forceinline__ float tanh_fast(float x) {
    // tanh(x) = (e-1)/(e+1), e = 2^(2x*log2(e)); clamp avoids inf/nan
    x = fminf(10.0f, fmaxf(-10.0f, x));
    float e = exp2f(x * 2.885390081777927f);
    return (e - 1.0f) * __builtin_amdgcn_rcpf(e + 1.0f);
}

// ---------------- K1: transpose + convert Wv -> WvT (bf16) ----------------
__global__ __launch_bounds__(256) void wvt_kernel(
    const float* __restrict__ Wv, __bf16* __restrict__ WvT) {
    int e = blockIdx.x * 256 + threadIdx.x;   // e = n*1024 + k
    int n = e >> 10, k = e & 1023;
    WvT[e] = (__bf16)Wv[(k << 10) + n];
}

// ---------------- small fp32 GEMM: C[128,1024] = act(A@W + b) -------------
// grid (4, 16, z): n-chunk 256 wide, 8 rows per block; A reads are
// wave-uniform -> scalar loads; W reads coalesced.
__global__ __launch_bounds__(256) void dual_gemm_k(
    const float* __restrict__ A0, const float* __restrict__ W0,
    const float* __restrict__ b0, float* __restrict__ C0, int act0,
    const float* __restrict__ A1, const float* __restrict__ W1,
    const float* __restrict__ b1, float* __restrict__ C1, int act1) {
    const float* A; const float* W; const float* bs; float* C; int act;
    if (blockIdx.z == 0) { A = A0; W = W0; bs = b0; C = C0; act = act0; }
    else                 { A = A1; W = W1; bs = b1; C = C1; act = act1; }
    int tid = threadIdx.x;
    int n = blockIdx.x * 256 + tid;
    int m0 = blockIdx.y * 8;
    const float* Ab = A + m0 * 1024;
    float acc[8];
    float bias = bs[n];
#pragma unroll
    for (int mi = 0; mi < 8; ++mi) acc[mi] = bias;
#pragma unroll 4
    for (int k = 0; k < 1024; ++k) {
        float w = W[k * 1024 + n];
#pragma unroll
        for (int mi = 0; mi < 8; ++mi)
            acc[mi] = fmaf(Ab[mi * 1024 + k], w, acc[mi]);
    }
#pragma unroll
    for (int mi = 0; mi < 8; ++mi) {
        float v = acc[mi];
        if (act == 1) v = fmaxf(v, 0.0f);
        else if (act == 2) v = tanh_fast(v);
        C[(m0 + mi) * 1024 + n] = v;
    }
}

// ---------------- K5: fused score GEMM ------------------------------------
// 128x128 tile, BK=32, 4 waves each computing a 64x64 quadrant via 4x4
// mfma_f32_16x16x32_bf16. A (=V rows) staged fp32->bf16 into padded LDS
// (row stride 40 bf16 -> 2-way-free frag reads). B (=WvT) staged via
// global_load_lds width 16 with XOR granule swizzle (2-way-free reads).
// Epilogue folds relu/+h_att/tanh/*Wal, reduces over n-lanes, atomicAdds.
__global__ __launch_bounds__(256, 2) void score_gemm_k(
    const float* __restrict__ V, const __bf16* __restrict__ WvT,
    const float* __restrict__ bv, const float* __restrict__ h_att,
    const float* __restrict__ Wal, float* __restrict__ scores) {
    __shared__ __bf16 As[128 * 40];   // padded: 32 used + 8 pad per row
    __shared__ __bf16 Bs[128 * 32];   // swizzled granules, contiguous for DMA

    const int tid = threadIdx.x;
    const int bid = blockIdx.x;
    // XCD grouping: 8 n-chunks of one m-stripe land consecutively on one XCD
    const int xcd = bid & 7;
    const int j = bid >> 3;
    const int mtile = xcd * 64 + (j >> 3);   // 0..511
    const int ntile = j & 7;                 // 0..7
    const int m0 = mtile * 128, n0 = ntile * 128;
    const int wid = tid >> 6, lane = tid & 63;
    const int wm = wid & 1, wn = wid >> 1;
    const int lcol = lane & 15, quad = lane >> 4;

    floatx4 acc[4][4] = {};

    const int am = tid >> 1;           // 0..127 (row of A tile)
    const int ak = (tid & 1) * 16;     // 0 or 16 (k offset)
    const float* aptr = V + (size_t)(m0 + am) * 1024 + ak;
    __bf16* awr = &As[am * 40 + ak];

    for (int kk = 0; kk < 32; ++kk) {
        const int k0 = kk * 32;
        // ---- B staging: 8KB via global_load_lds (wave-uniform base + lane*16)
#pragma unroll
        for (int c = 0; c < 2; ++c) {
            int g = c * 256 + tid;        // granule id in LDS
            int n = g >> 2, ks = g & 3;   // stored slot
            int kg = ks ^ ((n >> 1) & 3); // global k-octet (XOR swizzle)
            const __bf16* gp = WvT + (size_t)(n0 + n) * 1024 + (k0 + kg * 8);
            __builtin_amdgcn_global_load_lds(
                (const __attribute__((address_space(1))) void*)gp,
                (__attribute__((address_space(3))) void*)(&Bs[g * 8]),
                16, 0, 0);
        }
        // ---- A staging: fp32 vector loads -> bf16 -> ds_write_b128
        const float4* fp = reinterpret_cast<const float4*>(aptr + k0);
        float4 f0 = fp[0], f1 = fp[1], f2 = fp[2], f3 = fp[3];
        bf16x8 u0, u1;
        u0[0] = (__bf16)f0.x; u0[1] = (__bf16)f0.y;
        u0[2] = (__bf16)f0.z; u0[3] = (__bf16)f0.w;
        u0[4] = (__bf16)f1.x; u0[5] = (__bf16)f1.y;
        u0[6] = (__bf16)f1.z; u0[7] = (__bf16)f1.w;
        u1[0] = (__bf16)f2.x; u1[1] = (__bf16)f2.y;
        u1[2] = (__bf16)f2.z; u1[3] = (__bf16)f2.w;
        u1[4] = (__bf16)f3.x; u1[5] = (__bf16)f3.y;
        u1[6] = (__bf16)f3.z; u1[7] = (__bf16)f3.w;
        *reinterpret_cast<bf16x8*>(awr) = u0;
        *reinterpret_cast<bf16x8*>(awr + 8) = u1;
        __syncthreads();
        // ---- fragments + MFMA
        bf16x8 af[4], bfr[4];
#pragma unroll
        for (int mi = 0; mi < 4; ++mi)
            af[mi] = *reinterpret_cast<const bf16x8*>(
                &As[(wm * 64 + mi * 16 + lcol) * 40 + quad * 8]);
#pragma unroll
        for (int ni = 0; ni < 4; ++ni) {
            int n = wn * 64 + ni * 16 + lcol;
            int ks = quad ^ ((n >> 1) & 3);
            bfr[ni] = *reinterpret_cast<const bf16x8*>(&Bs[n * 32 + ks * 8]);
        }
#pragma unroll
        for (int mi = 0; mi < 4; ++mi)
#pragma unroll
            for (int ni = 0; ni < 4; ++ni)
                acc[mi][ni] = __builtin_amdgcn_mfma_f32_16x16x32_bf16(
                    af[mi], bfr[ni], acc[mi][ni], 0, 0, 0);
        __syncthreads();
    }

    // ---- epilogue: score partials ----
    const int b = m0 >> 9;   // uniform: 128 | 512
    float wal[4], hat[4], bvv[4];
#pragma unroll
    for (int ni = 0; ni < 4; ++ni) {
        int n = n0 + wn * 64 + ni * 16 + lcol;
        wal[ni] = Wal[n];
        hat[ni] = h_att[b * 1024 + n];
        bvv[ni] = bv[n];
    }
    float p[16];
#pragma unroll
    for (int mi = 0; mi < 4; ++mi) {
#pragma unroll
        for (int rg = 0; rg < 4; ++rg) {
            float s = 0.f;
#pragma unroll
            for (int ni = 0; ni < 4; ++ni) {
                float x = acc[mi][ni][rg] + bvv[ni];   // + bv
                x = fmaxf(x, 0.f);                      // relu
                s = fmaf(wal[ni], tanh_fast(x + hat[ni]), s);
            }
            p[mi * 4 + rg] = s;
        }
    }
    // reduce across the 16 n-lanes (low 4 lane bits)
#pragma unroll
    for (int off = 1; off < 16; off <<= 1) {
#pragma unroll
        for (int i = 0; i < 16; ++i) p[i] += __shfl_xor(p[i], off, 64);
    }
    if (lcol == 0) {
#pragma unroll
        for (int mi = 0; mi < 4; ++mi)
#pragma unroll
            for (int rg = 0; rg < 4; ++rg) {
                int row = m0 + wm * 64 + mi * 16 + quad * 4 + rg;
                atomicAdd(&scores[b * 513 + (row & 511)], p[mi * 4 + rg]);
            }
    }
}

// ---------------- K6: scores[b][512] from s_att/h_att ---------------------
__global__ __launch_bounds__(256) void lastrow_k(
    const float* __restrict__ s_att, const float* __restrict__ h_att,
    const float* __restrict__ Wal, float* __restrict__ scores) {
    int b = blockIdx.x, tid = threadIdx.x;
    float s = 0.f;
    for (int h = tid; h < 1024; h += 256)
        s += Wal[h] * tanh_fast(s_att[b * 1024 + h] + h_att[b * 1024 + h]);
#pragma unroll
    for (int off = 32; off >= 1; off >>= 1) s += __shfl_xor(s, off, 64);
    __shared__ float red[4];
    if ((tid & 63) == 0) red[tid >> 6] = s;
    __syncthreads();
    if (tid == 0) scores[b * 513 + 512] = red[0] + red[1] + red[2] + red[3];
}

// ---------------- K7: softmax over 513 ------------------------------------
__global__ __launch_bounds__(256) void softmax_k(
    const float* __restrict__ scores, float* __restrict__ alpha) {
    int b = blockIdx.x, tid = threadIdx.x;
    const float* s = scores + b * 513;
    float v0 = s[tid];
    float v1 = s[tid + 256];                       // 256..511 always valid
    float v2 = (tid == 0) ? s[512] : -1e30f;
    float m = fmaxf(v0, fmaxf(v1, v2));
#pragma unroll
    for (int off = 32; off >= 1; off >>= 1) m = fmaxf(m, __shfl_xor(m, off, 64));
    __shared__ float red[4];
    int w = tid >> 6;
    if ((tid & 63) == 0) red[w] = m;
    __syncthreads();
    m = fmaxf(fmaxf(red[0], red[1]), fmaxf(red[2], red[3]));
    const float L2E = 1.4426950408889634f;
    float e0 = exp2f((v0 - m) * L2E);
    float e1 = exp2f((v1 - m) * L2E);
    float e2 = (tid == 0) ? exp2f((v2 - m) * L2E) : 0.f;
    float sum = e0 + e1 + e2;
#pragma unroll
    for (int off = 32; off >= 1; off >>= 1) sum += __shfl_xor(sum, off, 64);
    __syncthreads();
    if ((tid & 63) == 0) red[w] = sum;
    __syncthreads();
    sum = red[0] + red[1] + red[2] + red[3];
    float inv = 1.0f / sum;
    float* a = alpha + b * 513;
    a[tid] = e0 * inv;
    a[tid + 256] = e1 * inv;
    if (tid == 0) a[512] = e2 * inv;
}

// ---------------- K8: context + h_proj ------------------------------------
// grid 256 = (b, half); 128 threads x float4 over 512 d's per half.
__global__ __launch_bounds__(128) void ctx_k(
    const float* __restrict__ V, const float* __restrict__ alpha,
    const float* __restrict__ s_proj, const float* __restrict__ h_proj,
    float* __restrict__ ctxsum) {
    int b = blockIdx.x >> 1, half = blockIdx.x & 1;
    int tid = threadIdx.x;
    __shared__ float sal[513];
    for (int i = tid; i < 513; i += 128) sal[i] = alpha[b * 513 + i];
    __syncthreads();
    int d0 = half * 512 + tid * 4;
    const float* vp = V + ((size_t)b * 512) * 1024 + d0;
    float a0 = 0, a1 = 0, a2 = 0, a3 = 0;
#pragma unroll 8
    for (int r = 0; r < 512; ++r) {
        float al = sal[r];
        const float4 vv = *reinterpret_cast<const float4*>(vp + (size_t)r * 1024);
        a0 = fmaf(al, vv.x, a0); a1 = fmaf(al, vv.y, a1);
        a2 = fmaf(al, vv.z, a2); a3 = fmaf(al, vv.w, a3);
    }
    float4 sp = *reinterpret_cast<const float4*>(s_proj + b * 1024 + d0);
    float4 hp = *reinterpret_cast<const float4*>(h_proj + b * 1024 + d0);
    float aR = sal[512];
    float4 o;
    o.x = fmaf(aR, sp.x, a0) + hp.x;
    o.y = fmaf(aR, sp.y, a1) + hp.y;
    o.z = fmaf(aR, sp.z, a2) + hp.z;
    o.w = fmaf(aR, sp.w, a3) + hp.w;
    *reinterpret_cast<float4*>(ctxsum + b * 1024 + d0) = o;
}

// ---------------------------------------------------------------------------
extern "C" void kernel_launch(void* const* d_in, const int* in_sizes, int n_in,
                              void* d_out, int out_size, void* d_ws,
                              size_t ws_size, hipStream_t stream) {
    const float* V   = (const float*)d_in[0];
    const float* s_t = (const float*)d_in[1];
    const float* h_t = (const float*)d_in[2];
    const float* Wv  = (const float*)d_in[3];
    const float* bv  = (const float*)d_in[4];
    const float* Wsp = (const float*)d_in[5];
    const float* bsp = (const float*)d_in[6];
    const float* Wsa = (const float*)d_in[7];
    const float* bsa = (const float*)d_in[8];
    const float* Whp = (const float*)d_in[9];
    const float* bhp = (const float*)d_in[10];
    const float* Wha = (const float*)d_in[11];
    const float* bha = (const float*)d_in[12];
    const float* Wal = (const float*)d_in[13];
    // d_in[14] = bal: constant shift of all softmax inputs -> dropped
    const float* Wcp = (const float*)d_in[15];
    const float* bcp = (const float*)d_in[16];
    float* out = (float*)d_out;

    char* ws = (char*)d_ws;
    __bf16* WvT   = (__bf16*)(ws + 0);         // 2 MB
    float* s_proj = (float*)(ws + 2097152);     // 512 KB
    float* h_proj = (float*)(ws + 2621440);     // 512 KB
    float* s_att  = (float*)(ws + 3145728);     // 512 KB
    float* h_att  = (float*)(ws + 3670016);     // 512 KB
    float* scores = (float*)(ws + 4194304);     // 128*513*4 = 262656 B
    float* alpha  = (float*)(ws + 4456960);     // 262656 B
    float* ctxsum = (float*)(ws + 4719616);     // 512 KB   (total ~5.2 MB)

    hipLaunchKernelGGL(wvt_kernel, dim3(4096), dim3(256), 0, stream, Wv, WvT);
    hipLaunchKernelGGL(dual_gemm_k, dim3(4, 16, 2), dim3(256), 0, stream,
                       s_t, Wsp, bsp, s_proj, 1,
                       h_t, Whp, bhp, h_proj, 2);
    hipLaunchKernelGGL(dual_gemm_k, dim3(4, 16, 2), dim3(256), 0, stream,
                       s_proj, Wsa, bsa, s_att, 0,
                       h_proj, Wha, bha, h_att, 0);
    (void)hipMemsetAsync(scores, 0, 128 * 513 * sizeof(float), stream);
    hipLaunchKernelGGL(score_gemm_k, dim3(4096), dim3(256), 0, stream,
                       V, WvT, bv, h_att, Wal, scores);
    hipLaunchKernelGGL(lastrow_k, dim3(128), dim3(256), 0, stream,
                       s_att, h_att, Wal, scores);
    hipLaunchKernelGGL(softmax_k, dim3(128), dim3(256), 0, stream,
                       scores, alpha);
    hipLaunchKernelGGL(ctx_k, dim3(256), dim3(128), 0, stream,
                       V, alpha, s_proj, h_proj, ctxsum);
    hipLaunchKernelGGL(dual_gemm_k, dim3(4, 16, 1), dim3(256), 0, stream,
                       ctxsum, Wcp, bcp, out, 2,
                       ctxsum, Wcp, bcp, out, 2);
}

// Round 2
// 879.001 us; speedup vs baseline: 1.3239x; 1.3239x over previous
//
#include <hip/hip_runtime.h>

// ---------------------------------------------------------------------------
// AttentionLayer fused implementation for MI355X (gfx950)  -- Round 2
// D=H=1024, B=128, R=512, M=B*R=65536
//
// R2 changes vs R1 (theory: everything was latency-bound, nothing was busy):
//  * score_gemm_k: double-buffered LDS (A and B); next-step global_load_lds
//    DMA + fp32 A prefetch issued BEFORE current-step MFMAs -> latency hidden
//    behind compute across ~12 waves/CU instead of serialized per K-step.
//  * small_gemm_k: 4-way K-split within a 512-thread block + LDS reduce;
//    256 blocks (was 128) -> 8 waves/CU instead of 1 wave/SIMD.
//  * ctx_k: 512 blocks x 4 waves, 4-way R-split + LDS reduce -> HBM-bound.
//  * wvt_kernel: LDS-tiled 64x64 transpose, coalesced on both sides.
// ---------------------------------------------------------------------------

typedef __bf16 bf16x8 __attribute__((ext_vector_type(8)));
typedef float floatx4 __attribute__((ext_vector_type(4)));

__device__ __forceinline__ float tanh_fast(float x) {
    x = fminf(10.0f, fmaxf(-10.0f, x));
    float e = exp2f(x * 2.885390081777927f);
    return (e - 1.0f) * __builtin_amdgcn_rcpf(e + 1.0f);
}

// ---------------- K1: transpose + convert Wv -> WvT (bf16) ----------------
// 64x64 tile per block, grid (16,16). Coalesced reads (256B/wave) and
// coalesced bf16 writes (128B/wave); LDS stride 65 -> conflict-free.
__global__ __launch_bounds__(256) void wvt_kernel(
    const float* __restrict__ Wv, __bf16* __restrict__ WvT) {
    __shared__ float tile[64][65];
    const int k0 = blockIdx.x * 64, n0 = blockIdx.y * 64;
    const int c = threadIdx.x & 63, r = threadIdx.x >> 6;  // 4 rows/pass
#pragma unroll
    for (int i = 0; i < 16; ++i)
        tile[r + i * 4][c] = Wv[(size_t)(k0 + r + i * 4) * 1024 + n0 + c];
    __syncthreads();
#pragma unroll
    for (int i = 0; i < 16; ++i)
        WvT[(size_t)(n0 + r + i * 4) * 1024 + k0 + c] =
            (__bf16)tile[c][r + i * 4];
}

// ---------------- small fp32 GEMM: C[128,1024] = act(A@W + b) -------------
// grid (8, 16, z), block 512: tid&127 = n within 128-chunk, tid>>7 = k-quarter
// (256 k's each). LDS reduce across the 4 quarters, then bias+activation.
__global__ __launch_bounds__(512) void small_gemm_k(
    const float* __restrict__ A0, const float* __restrict__ W0,
    const float* __restrict__ b0, float* __restrict__ C0, int act0,
    const float* __restrict__ A1, const float* __restrict__ W1,
    const float* __restrict__ b1, float* __restrict__ C1, int act1) {
    const float* A; const float* W; const float* bs; float* C; int act;
    if (blockIdx.z == 0) { A = A0; W = W0; bs = b0; C = C0; act = act0; }
    else                 { A = A1; W = W1; bs = b1; C = C1; act = act1; }
    __shared__ float red[3][8][128];
    const int tid = threadIdx.x;
    const int nl = tid & 127, kq = tid >> 7;
    const int n = blockIdx.x * 128 + nl;
    const int m0 = blockIdx.y * 8;
    const float* Ab = A + m0 * 1024;
    float acc[8] = {};
    const int kbeg = kq * 256, kend = kbeg + 256;
#pragma unroll 4
    for (int k = kbeg; k < kend; ++k) {
        float w = W[(size_t)k * 1024 + n];
#pragma unroll
        for (int mi = 0; mi < 8; ++mi)
            acc[mi] = fmaf(Ab[mi * 1024 + k], w, acc[mi]);
    }
    if (kq > 0) {
#pragma unroll
        for (int mi = 0; mi < 8; ++mi) red[kq - 1][mi][nl] = acc[mi];
    }
    __syncthreads();
    if (kq == 0) {
        float bias = bs[n];
#pragma unroll
        for (int mi = 0; mi < 8; ++mi) {
            float v = acc[mi] + red[0][mi][nl] + red[1][mi][nl] +
                      red[2][mi][nl] + bias;
            if (act == 1) v = fmaxf(v, 0.0f);
            else if (act == 2) v = tanh_fast(v);
            C[(size_t)(m0 + mi) * 1024 + n] = v;
        }
    }
}

// ---------------- K5: fused score GEMM (double-buffered) ------------------
// 128x128 tile, BK=32, 4 waves x (64x64 via 4x4 mfma_f32_16x16x32_bf16).
// Double-buffered LDS; next-step B DMA (global_load_lds w=16) and fp32 A
// prefetch issued before current-step MFMAs. Epilogue folds bv/relu/h_att/
// tanh/Wal-dot, shuffle-reduces 16 n-lanes, atomicAdds into scores.
__global__ __launch_bounds__(256, 3) void score_gemm_k(
    const float* __restrict__ V, const __bf16* __restrict__ WvT,
    const float* __restrict__ bv, const float* __restrict__ h_att,
    const float* __restrict__ Wal, float* __restrict__ scores) {
    __shared__ __bf16 As[2][128 * 40];   // padded rows: 32 used + 8 pad
    __shared__ __bf16 Bs[2][128 * 32];   // XOR-swizzled k-octets

    const int tid = threadIdx.x;
    const int bid = blockIdx.x;
    const int xcd = bid & 7;
    const int j = bid >> 3;
    const int mtile = xcd * 64 + (j >> 3);   // 0..511
    const int ntile = j & 7;                 // 0..7
    const int m0 = mtile * 128, n0 = ntile * 128;
    const int wid = tid >> 6, lane = tid & 63;
    const int wm = wid & 1, wn = wid >> 1;
    const int lcol = lane & 15, quad = lane >> 4;

    floatx4 acc[4][4] = {};

    const int am = tid >> 1;           // A-tile row 0..127
    const int ak = (tid & 1) * 16;     // k offset 0|16
    const float* aptr = V + (size_t)(m0 + am) * 1024 + ak;

    // B granule mapping (per thread, per chunk c): granule g = c*256+tid
    const int g0n = tid >> 2, g0ks = tid & 3;
    const int g1n = (256 + tid) >> 2, g1ks = tid & 3;
    const int g0kg = g0ks ^ ((g0n >> 1) & 3);
    const int g1kg = g1ks ^ ((g1n >> 1) & 3);
    const __bf16* bp0 = WvT + (size_t)(n0 + g0n) * 1024 + g0kg * 8;
    const __bf16* bp1 = WvT + (size_t)(n0 + g1n) * 1024 + g1kg * 8;

    auto stage_A = [&](int buf, float4 f0, float4 f1, float4 f2, float4 f3) {
        bf16x8 u0, u1;
        u0[0] = (__bf16)f0.x; u0[1] = (__bf16)f0.y;
        u0[2] = (__bf16)f0.z; u0[3] = (__bf16)f0.w;
        u0[4] = (__bf16)f1.x; u0[5] = (__bf16)f1.y;
        u0[6] = (__bf16)f1.z; u0[7] = (__bf16)f1.w;
        u1[0] = (__bf16)f2.x; u1[1] = (__bf16)f2.y;
        u1[2] = (__bf16)f2.z; u1[3] = (__bf16)f2.w;
        u1[4] = (__bf16)f3.x; u1[5] = (__bf16)f3.y;
        u1[6] = (__bf16)f3.z; u1[7] = (__bf16)f3.w;
        __bf16* awr = &As[buf][am * 40 + ak];
        *reinterpret_cast<bf16x8*>(awr) = u0;
        *reinterpret_cast<bf16x8*>(awr + 8) = u1;
    };
    auto dma_B = [&](int buf, int k0) {
        __builtin_amdgcn_global_load_lds(
            (const __attribute__((address_space(1))) void*)(bp0 + k0),
            (__attribute__((address_space(3))) void*)(&Bs[buf][tid * 8]),
            16, 0, 0);
        __builtin_amdgcn_global_load_lds(
            (const __attribute__((address_space(1))) void*)(bp1 + k0),
            (__attribute__((address_space(3))) void*)(&Bs[buf][(256 + tid) * 8]),
            16, 0, 0);
    };

    // ---- prologue: stage step 0 into buffer 0
    dma_B(0, 0);
    {
        const float4* fp = reinterpret_cast<const float4*>(aptr);
        stage_A(0, fp[0], fp[1], fp[2], fp[3]);
    }
    __syncthreads();

    for (int kk = 0; kk < 32; ++kk) {
        const int cur = kk & 1, nxt = cur ^ 1;
        float4 f0, f1, f2, f3;
        const bool pf = (kk < 31);
        if (pf) {
            dma_B(nxt, (kk + 1) * 32);                       // B DMA, in flight
            const float4* fp =
                reinterpret_cast<const float4*>(aptr + (kk + 1) * 32);
            f0 = fp[0]; f1 = fp[1]; f2 = fp[2]; f3 = fp[3];  // A prefetch
        }
        // ---- current-step fragments + MFMA
        bf16x8 af[4], bfr[4];
#pragma unroll
        for (int mi = 0; mi < 4; ++mi)
            af[mi] = *reinterpret_cast<const bf16x8*>(
                &As[cur][(wm * 64 + mi * 16 + lcol) * 40 + quad * 8]);
#pragma unroll
        for (int ni = 0; ni < 4; ++ni) {
            int n = wn * 64 + ni * 16 + lcol;
            int ks = quad ^ ((n >> 1) & 3);
            bfr[ni] = *reinterpret_cast<const bf16x8*>(
                &Bs[cur][n * 32 + ks * 8]);
        }
#pragma unroll
        for (int mi = 0; mi < 4; ++mi)
#pragma unroll
            for (int ni = 0; ni < 4; ++ni)
                acc[mi][ni] = __builtin_amdgcn_mfma_f32_16x16x32_bf16(
                    af[mi], bfr[ni], acc[mi][ni], 0, 0, 0);
        if (pf) stage_A(nxt, f0, f1, f2, f3);   // convert after MFMAs
        __syncthreads();   // drains DMA(nxt) + ds_write(nxt) for next step
    }

    // ---- epilogue: fused score partials ----
    const int b = m0 >> 9;
    float wal[4], hat[4], bvv[4];
#pragma unroll
    for (int ni = 0; ni < 4; ++ni) {
        int n = n0 + wn * 64 + ni * 16 + lcol;
        wal[ni] = Wal[n];
        hat[ni] = h_att[b * 1024 + n];
        bvv[ni] = bv[n];
    }
    float p[16];
#pragma unroll
    for (int mi = 0; mi < 4; ++mi) {
#pragma unroll
        for (int rg = 0; rg < 4; ++rg) {
            float s = 0.f;
#pragma unroll
            for (int ni = 0; ni < 4; ++ni) {
                float x = acc[mi][ni][rg] + bvv[ni];
                x = fmaxf(x, 0.f);
                s = fmaf(wal[ni], tanh_fast(x + hat[ni]), s);
            }
            p[mi * 4 + rg] = s;
        }
    }
#pragma unroll
    for (int off = 1; off < 16; off <<= 1) {
#pragma unroll
        for (int i = 0; i < 16; ++i) p[i] += __shfl_xor(p[i], off, 64);
    }
    if (lcol == 0) {
#pragma unroll
        for (int mi = 0; mi < 4; ++mi)
#pragma unroll
            for (int rg = 0; rg < 4; ++rg) {
                int row = m0 + wm * 64 + mi * 16 + quad * 4 + rg;
                atomicAdd(&scores[b * 513 + (row & 511)], p[mi * 4 + rg]);
            }
    }
}

// ---------------- K6: scores[b][512] from s_att/h_att ---------------------
__global__ __launch_bounds__(256) void lastrow_k(
    const float* __restrict__ s_att, const float* __restrict__ h_att,
    const float* __restrict__ Wal, float* __restrict__ scores) {
    int b = blockIdx.x, tid = threadIdx.x;
    float s = 0.f;
    for (int h = tid; h < 1024; h += 256)
        s += Wal[h] * tanh_fast(s_att[b * 1024 + h] + h_att[b * 1024 + h]);
#pragma unroll
    for (int off = 32; off >= 1; off >>= 1) s += __shfl_xor(s, off, 64);
    __shared__ float red[4];
    if ((tid & 63) == 0) red[tid >> 6] = s;
    __syncthreads();
    if (tid == 0) scores[b * 513 + 512] = red[0] + red[1] + red[2] + red[3];
}

// ---------------- K7: softmax over 513 ------------------------------------
__global__ __launch_bounds__(256) void softmax_k(
    const float* __restrict__ scores, float* __restrict__ alpha) {
    int b = blockIdx.x, tid = threadIdx.x;
    const float* s = scores + b * 513;
    float v0 = s[tid];
    float v1 = s[tid + 256];
    float v2 = (tid == 0) ? s[512] : -1e30f;
    float m = fmaxf(v0, fmaxf(v1, v2));
#pragma unroll
    for (int off = 32; off >= 1; off >>= 1) m = fmaxf(m, __shfl_xor(m, off, 64));
    __shared__ float red[4];
    int w = tid >> 6;
    if ((tid & 63) == 0) red[w] = m;
    __syncthreads();
    m = fmaxf(fmaxf(red[0], red[1]), fmaxf(red[2], red[3]));
    const float L2E = 1.4426950408889634f;
    float e0 = exp2f((v0 - m) * L2E);
    float e1 = exp2f((v1 - m) * L2E);
    float e2 = (tid == 0) ? exp2f((v2 - m) * L2E) : 0.f;
    float sum = e0 + e1 + e2;
#pragma unroll
    for (int off = 32; off >= 1; off >>= 1) sum += __shfl_xor(sum, off, 64);
    __syncthreads();
    if ((tid & 63) == 0) red[w] = sum;
    __syncthreads();
    sum = red[0] + red[1] + red[2] + red[3];
    float inv = 1.0f / sum;
    float* a = alpha + b * 513;
    a[tid] = e0 * inv;
    a[tid + 256] = e1 * inv;
    if (tid == 0) a[512] = e2 * inv;
}

// ---------------- K8: context + h_proj ------------------------------------
// grid (128,4): b, d-quarter (256 d's). Block 256: tid&63 = float4 slot,
// tid>>6 = r-quarter (128 rows). LDS reduce across r-quarters.
__global__ __launch_bounds__(256) void ctx_k(
    const float* __restrict__ V, const float* __restrict__ alpha,
    const float* __restrict__ s_proj, const float* __restrict__ h_proj,
    float* __restrict__ ctxsum) {
    const int b = blockIdx.x, dq = blockIdx.y;
    const int tid = threadIdx.x;
    const int dl = tid & 63, rq = tid >> 6;
    __shared__ float sal[513];
    __shared__ float red[3][64][4];
    for (int i = tid; i < 513; i += 256) sal[i] = alpha[b * 513 + i];
    __syncthreads();
    const int d0 = dq * 256 + dl * 4;
    const float* vp = V + ((size_t)b * 512 + rq * 128) * 1024 + d0;
    float a0 = 0, a1 = 0, a2 = 0, a3 = 0;
#pragma unroll 8
    for (int r = 0; r < 128; ++r) {
        float al = sal[rq * 128 + r];
        const float4 vv = *reinterpret_cast<const float4*>(vp + (size_t)r * 1024);
        a0 = fmaf(al, vv.x, a0); a1 = fmaf(al, vv.y, a1);
        a2 = fmaf(al, vv.z, a2); a3 = fmaf(al, vv.w, a3);
    }
    if (rq > 0) {
        red[rq - 1][dl][0] = a0; red[rq - 1][dl][1] = a1;
        red[rq - 1][dl][2] = a2; red[rq - 1][dl][3] = a3;
    }
    __syncthreads();
    if (rq == 0) {
#pragma unroll
        for (int q = 0; q < 3; ++q) {
            a0 += red[q][dl][0]; a1 += red[q][dl][1];
            a2 += red[q][dl][2]; a3 += red[q][dl][3];
        }
        float4 sp = *reinterpret_cast<const float4*>(s_proj + b * 1024 + d0);
        float4 hp = *reinterpret_cast<const float4*>(h_proj + b * 1024 + d0);
        float aR = sal[512];
        float4 o;
        o.x = fmaf(aR, sp.x, a0) + hp.x;
        o.y = fmaf(aR, sp.y, a1) + hp.y;
        o.z = fmaf(aR, sp.z, a2) + hp.z;
        o.w = fmaf(aR, sp.w, a3) + hp.w;
        *reinterpret_cast<float4*>(ctxsum + b * 1024 + d0) = o;
    }
}

// ---------------------------------------------------------------------------
extern "C" void kernel_launch(void* const* d_in, const int* in_sizes, int n_in,
                              void* d_out, int out_size, void* d_ws,
                              size_t ws_size, hipStream_t stream) {
    const float* V   = (const float*)d_in[0];
    const float* s_t = (const float*)d_in[1];
    const float* h_t = (const float*)d_in[2];
    const float* Wv  = (const float*)d_in[3];
    const float* bv  = (const float*)d_in[4];
    const float* Wsp = (const float*)d_in[5];
    const float* bsp = (const float*)d_in[6];
    const float* Wsa = (const float*)d_in[7];
    const float* bsa = (const float*)d_in[8];
    const float* Whp = (const float*)d_in[9];
    const float* bhp = (const float*)d_in[10];
    const float* Wha = (const float*)d_in[11];
    const float* bha = (const float*)d_in[12];
    const float* Wal = (const float*)d_in[13];
    // d_in[14] = bal: softmax-invariant constant -> dropped
    const float* Wcp = (const float*)d_in[15];
    const float* bcp = (const float*)d_in[16];
    float* out = (float*)d_out;

    char* ws = (char*)d_ws;
    __bf16* WvT   = (__bf16*)(ws + 0);          // 2 MB
    float* s_proj = (float*)(ws + 2097152);      // 512 KB
    float* h_proj = (float*)(ws + 2621440);      // 512 KB
    float* s_att  = (float*)(ws + 3145728);      // 512 KB
    float* h_att  = (float*)(ws + 3670016);      // 512 KB
    float* scores = (float*)(ws + 4194304);      // 262656 B
    float* alpha  = (float*)(ws + 4456960);      // 262656 B
    float* ctxsum = (float*)(ws + 4719616);      // 512 KB

    hipLaunchKernelGGL(wvt_kernel, dim3(16, 16), dim3(256), 0, stream, Wv, WvT);
    hipLaunchKernelGGL(small_gemm_k, dim3(8, 16, 2), dim3(512), 0, stream,
                       s_t, Wsp, bsp, s_proj, 1,
                       h_t, Whp, bhp, h_proj, 2);
    hipLaunchKernelGGL(small_gemm_k, dim3(8, 16, 2), dim3(512), 0, stream,
                       s_proj, Wsa, bsa, s_att, 0,
                       h_proj, Wha, bha, h_att, 0);
    (void)hipMemsetAsync(scores, 0, 128 * 513 * sizeof(float), stream);
    hipLaunchKernelGGL(score_gemm_k, dim3(4096), dim3(256), 0, stream,
                       V, WvT, bv, h_att, Wal, scores);
    hipLaunchKernelGGL(lastrow_k, dim3(128), dim3(256), 0, stream,
                       s_att, h_att, Wal, scores);
    hipLaunchKernelGGL(softmax_k, dim3(128), dim3(256), 0, stream,
                       scores, alpha);
    hipLaunchKernelGGL(ctx_k, dim3(128, 4), dim3(256), 0, stream,
                       V, alpha, s_proj, h_proj, ctxsum);
    hipLaunchKernelGGL(small_gemm_k, dim3(8, 16, 1), dim3(512), 0, stream,
                       ctxsum, Wcp, bcp, out, 2,
                       ctxsum, Wcp, bcp, out, 2);
}